// Round 6
// baseline (123.566 us; speedup 1.0000x reference)
//
#include <hip/hip_runtime.h>
#include <hip/hip_bf16.h>
#include <cstdint>

#define DEVI static __device__ __forceinline__

typedef __attribute__((ext_vector_type(8))) short s16x8;     // 8 bf16 (MFMA frag)
typedef __attribute__((ext_vector_type(4))) float f32x4;
typedef __attribute__((ext_vector_type(2))) unsigned int u32x2;

DEVI unsigned short f2bf(float f) {  // f32 -> bf16 bits, RNE
  union { float f; unsigned int u; } v; v.f = f;
  return (unsigned short)((v.u + 0x7FFFu + ((v.u >> 16) & 1u)) >> 16);
}

DEVI unsigned int pk2bf(float a, float b) {  // pack 2 f32 -> 2 bf16 (v_cvt_pk)
  __hip_bfloat162 h2 = __float22bfloat162_rn(float2{a, b});
  return *(unsigned int*)&h2;
}

DEVI void g2l16(const void* g, void* l) {  // async global->LDS, 16B/lane, wave-uniform LDS base
  __builtin_amdgcn_global_load_lds((const __attribute__((address_space(1))) void*)g,
                                   (__attribute__((address_space(3))) void*)l, 16, 0, 0);
}

// ---------------- prep: f32->bf16 cvt (y=0..2) + mask flags (y=3) + weight transpose (y=4) ----------------
__global__ __launch_bounds__(256) void prep_kernel(const float* __restrict__ a,
                                                   const float* __restrict__ b,
                                                   const float* __restrict__ c,
                                                   const float* __restrict__ energy,
                                                   unsigned short* __restrict__ oa,
                                                   unsigned short* __restrict__ ob,
                                                   unsigned short* __restrict__ oc,
                                                   int* __restrict__ flags,
                                                   const float* __restrict__ W0,
                                                   const float* __restrict__ W1,
                                                   const float* __restrict__ W2,
                                                   const float* __restrict__ W3,
                                                   unsigned short* __restrict__ T0,
                                                   unsigned short* __restrict__ T1,
                                                   unsigned short* __restrict__ T2,
                                                   unsigned short* __restrict__ T3) {
  const int t = threadIdx.x;
  __shared__ float lds[64][65];
  if (blockIdx.y == 4) {  // W (K,N) f32 -> WT (N,K) bf16, 4 matrices x 256 tiles
    const int x = blockIdx.x;
    if (x >= 1024) return;
    const int z = x >> 8, rem = x & 255;
    const float* W = z == 0 ? W0 : z == 1 ? W1 : z == 2 ? W2 : W3;
    unsigned short* WT = z == 0 ? T0 : z == 1 ? T1 : z == 2 ? T2 : T3;
    const int n0 = (rem >> 4) * 64, k0 = (rem & 15) * 64;
#pragma unroll
    for (int p = 0; p < 4; p++) {
      int r = p * 16 + (t >> 4);
      int cc = (t & 15) * 4;
      f32x4 v = *(const f32x4*)(W + (size_t)(k0 + r) * 1024 + n0 + cc);
      lds[r][cc] = v[0]; lds[r][cc + 1] = v[1]; lds[r][cc + 2] = v[2]; lds[r][cc + 3] = v[3];
    }
    __syncthreads();
    const int cc = t >> 2, gk = t & 3;
#pragma unroll
    for (int hv = 0; hv < 2; hv++) {
      s16x8 o;
#pragma unroll
      for (int j = 0; j < 8; j++) o[j] = (short)f2bf(lds[gk * 16 + hv * 8 + j][cc]);
      *(s16x8*)(WT + (size_t)(n0 + cc) * 1024 + k0 + gk * 16 + hv * 8) = o;
    }
    return;
  }
  if (blockIdx.y == 3) {  // mask: one row per block (4096 rows)
    const int row = blockIdx.x;
    f32x4 v = *(const f32x4*)(energy + (size_t)row * 1024 + t * 4);
    float s = fabsf(v[0]) + fabsf(v[1]) + fabsf(v[2]) + fabsf(v[3]);
#pragma unroll
    for (int off = 1; off < 64; off <<= 1) s += __shfl_xor(s, off);
    if ((t & 63) == 0) lds[0][t >> 6] = s;
    __syncthreads();
    if (t == 0) {
      float tot = lds[0][0] + lds[0][1] + lds[0][2] + lds[0][3];
      flags[row] = (tot * (1.0f / 1024.0f) > 0.8f) ? 1 : 0;
    }
    return;
  }
  if (blockIdx.x >= 2048) return;
  const float* in = blockIdx.y == 0 ? a : blockIdx.y == 1 ? b : c;
  unsigned short* out = blockIdx.y == 0 ? oa : blockIdx.y == 1 ? ob : oc;
  int i = (blockIdx.x * 256 + t) * 8;
  f32x4 x = *(const f32x4*)(in + i);
  f32x4 y = *(const f32x4*)(in + i + 4);
  s16x8 o;
  o[0] = (short)f2bf(x[0]); o[1] = (short)f2bf(x[1]);
  o[2] = (short)f2bf(x[2]); o[3] = (short)f2bf(x[3]);
  o[4] = (short)f2bf(y[0]); o[5] = (short)f2bf(y[1]);
  o[6] = (short)f2bf(y[2]); o[7] = (short)f2bf(y[3]);
  *(s16x8*)(out + i) = o;
}

// ---------------- exclusive-scan of flags -> compact positions + count (1 block/batch) ----------------
__global__ __launch_bounds__(256) void scan_kernel(const int* __restrict__ flags,
                                                   int* __restrict__ pos,
                                                   int* __restrict__ cnt) {
  const int b = blockIdx.x, t = threadIdx.x;
  const int* f = flags + b * 2048;
  int loc[8], s = 0;
#pragma unroll
  for (int j = 0; j < 8; j++) { loc[j] = f[t * 8 + j]; s += loc[j]; }
  const int lane = t & 63, w = t >> 6;
  int ps = s;
#pragma unroll
  for (int off = 1; off < 64; off <<= 1) {
    int o = __shfl_up(ps, off);
    if (lane >= off) ps += o;
  }
  __shared__ int wsum[4];
  if (lane == 63) wsum[w] = ps;
  __syncthreads();
  int woff = 0;
  for (int i = 0; i < w; i++) woff += wsum[i];
  int excl = woff + ps - s;
  int* p = pos + b * 2048;
#pragma unroll
  for (int j = 0; j < 8; j++) { p[t * 8 + j] = loc[j] ? excl : -1; excl += loc[j]; }
  if (t == 255) cnt[b] = woff + ps;
}

// ---------------- fused Q/K/V projection, 128x128 tile (m97 structure, 3 blocks/CU) ----------------
// z=0: Q row-major (B,L,D) bf16, scaled by qsc
// z=1: K compacted scatter (B,H,Lc,Dh) bf16
// z=2: V^T compacted scatter (B,H,Dh,Lc) bf16
__global__ __launch_bounds__(256) void proj_qkv(const unsigned short* __restrict__ xq,
                                                const unsigned short* __restrict__ xk,
                                                const unsigned short* __restrict__ xv,
                                                const unsigned short* __restrict__ WTq,
                                                const unsigned short* __restrict__ WTk,
                                                const unsigned short* __restrict__ WTv,
                                                const float* __restrict__ bq,
                                                const float* __restrict__ bk,
                                                const float* __restrict__ bv,
                                                unsigned short* __restrict__ Qb,
                                                unsigned short* __restrict__ Kc,
                                                unsigned short* __restrict__ VTc,
                                                const int* __restrict__ pos,
                                                float qsc) {
  const int z = blockIdx.z;
  const unsigned short* A  = z == 0 ? xq : z == 1 ? xk : xv;
  const unsigned short* BT = z == 0 ? WTq : z == 1 ? WTk : WTv;
  const float* bias        = z == 0 ? bq : z == 1 ? bk : bv;
  const int m0 = blockIdx.x * 128;
  const int n0 = blockIdx.y * 128;
  const int t = threadIdx.x;
  const int w = t >> 6, lane = t & 63;
  const int wr = w >> 1, wc = w & 1;     // wave grid 2x2, each wave owns 64x64
  const int lr = lane & 15, lg = lane >> 4;

  __shared__ __align__(16) unsigned short As[128 * 64];  // 128 rows x 128B (BK=64)
  __shared__ __align__(16) unsigned short Bs[128 * 64];

  f32x4 acc[4][4] = {};

  const int sr = lane >> 3, sg = lane & 7;
  for (int kt = 0; kt < 1024; kt += 64) {
#pragma unroll
    for (int i = 0; i < 4; i++) {
      int r = (i * 4 + w) * 8 + sr;
      g2l16(A + (size_t)(m0 + r) * 1024 + kt + (sg ^ (r & 7)) * 8,
            (char*)As + (i * 4 + w) * 1024);
      g2l16(BT + (size_t)(n0 + r) * 1024 + kt + (sg ^ (r & 7)) * 8,
            (char*)Bs + (i * 4 + w) * 1024);
    }
    __syncthreads();
#pragma unroll
    for (int ks = 0; ks < 2; ks++) {
      s16x8 af[4], bf[4];
#pragma unroll
      for (int mi = 0; mi < 4; mi++) {
        int row = wr * 64 + mi * 16 + lr;
        af[mi] = *(const s16x8*)((const char*)As + row * 128 + (((ks * 4 + lg) ^ (row & 7)) * 16));
      }
#pragma unroll
      for (int nj = 0; nj < 4; nj++) {
        int row = wc * 64 + nj * 16 + lr;
        bf[nj] = *(const s16x8*)((const char*)Bs + row * 128 + (((ks * 4 + lg) ^ (row & 7)) * 16));
      }
#pragma unroll
      for (int mi = 0; mi < 4; mi++)
#pragma unroll
        for (int nj = 0; nj < 4; nj++)
          acc[mi][nj] = __builtin_amdgcn_mfma_f32_16x16x32_bf16(af[mi], bf[nj], acc[mi][nj], 0, 0, 0);
    }
    __syncthreads();
  }

  float bv2[4];
#pragma unroll
  for (int nj = 0; nj < 4; nj++) bv2[nj] = bias[n0 + wc * 64 + nj * 16 + lr];

#pragma unroll
  for (int mi = 0; mi < 4; mi++) {
    const int mb = m0 + wr * 64 + mi * 16 + lg * 4;  // C row = (lane>>4)*4 + reg  [m89 layout]
#pragma unroll
    for (int nj = 0; nj < 4; nj++) {
      const int n = n0 + wc * 64 + nj * 16 + lr;     // C col = lane&15
      if (z == 0) {
#pragma unroll
        for (int rg = 0; rg < 4; rg++)
          Qb[(size_t)(mb + rg) * 1024 + n] = f2bf((acc[mi][nj][rg] + bv2[nj]) * qsc);
      } else if (z == 1) {  // K compacted (B,H,Lc,Dh)
        const int h = n >> 6, dh = n & 63;
#pragma unroll
        for (int rg = 0; rg < 4; rg++) {
          int m = mb + rg;
          int b = m >> 11;
          int cp = pos[m];
          if (cp >= 0)
            Kc[((size_t)(b * 16 + h) * 2048 + cp) * 64 + dh] = f2bf(acc[mi][nj][rg] + bv2[nj]);
        }
      } else {  // V^T compacted (B,H,Dh,Lc)
        const int h = n >> 6, dh = n & 63;
#pragma unroll
        for (int rg = 0; rg < 4; rg++) {
          int m = mb + rg;
          int b = m >> 11;
          int cp = pos[m];
          if (cp >= 0)
            VTc[((size_t)(b * 16 + h) * 64 + dh) * 2048 + cp] = f2bf(acc[mi][nj][rg] + bv2[nj]);
        }
      }
    }
  }
}

// ---------------- output projection: 128x64 tile (2 blocks/CU at N=1024), f32 out ----------------
__global__ __launch_bounds__(256) void gemm_out(const unsigned short* __restrict__ A,
                                                const unsigned short* __restrict__ BT,
                                                const float* __restrict__ bias,
                                                float* __restrict__ out) {
  const int m0 = blockIdx.x * 128;
  const int n0 = blockIdx.y * 64;
  const int t = threadIdx.x;
  const int w = t >> 6, lane = t & 63;
  const int wr = w >> 1, wc = w & 1;
  const int lr = lane & 15, lg = lane >> 4;

  __shared__ __align__(16) unsigned short As[128 * 64];
  __shared__ __align__(16) unsigned short Bs[64 * 64];

  f32x4 acc[4][2] = {};

  const int sr = lane >> 3, sg = lane & 7;
  for (int kt = 0; kt < 1024; kt += 64) {
#pragma unroll
    for (int i = 0; i < 4; i++) {
      int r = (i * 4 + w) * 8 + sr;
      g2l16(A + (size_t)(m0 + r) * 1024 + kt + (sg ^ (r & 7)) * 8,
            (char*)As + (i * 4 + w) * 1024);
    }
#pragma unroll
    for (int i = 0; i < 2; i++) {
      int r = (i * 4 + w) * 8 + sr;
      g2l16(BT + (size_t)(n0 + r) * 1024 + kt + (sg ^ (r & 7)) * 8,
            (char*)Bs + (i * 4 + w) * 1024);
    }
    __syncthreads();
#pragma unroll
    for (int ks = 0; ks < 2; ks++) {
      s16x8 af[4], bf[2];
#pragma unroll
      for (int mi = 0; mi < 4; mi++) {
        int row = wr * 64 + mi * 16 + lr;
        af[mi] = *(const s16x8*)((const char*)As + row * 128 + (((ks * 4 + lg) ^ (row & 7)) * 16));
      }
#pragma unroll
      for (int nj = 0; nj < 2; nj++) {
        int row = wc * 32 + nj * 16 + lr;
        bf[nj] = *(const s16x8*)((const char*)Bs + row * 128 + (((ks * 4 + lg) ^ (row & 7)) * 16));
      }
#pragma unroll
      for (int mi = 0; mi < 4; mi++)
#pragma unroll
        for (int nj = 0; nj < 2; nj++)
          acc[mi][nj] = __builtin_amdgcn_mfma_f32_16x16x32_bf16(af[mi], bf[nj], acc[mi][nj], 0, 0, 0);
    }
    __syncthreads();
  }

  float bv2[2];
#pragma unroll
  for (int nj = 0; nj < 2; nj++) bv2[nj] = bias[n0 + wc * 32 + nj * 16 + lr];

#pragma unroll
  for (int mi = 0; mi < 4; mi++) {
    const int mb = m0 + wr * 64 + mi * 16 + lg * 4;
#pragma unroll
    for (int nj = 0; nj < 2; nj++) {
      const int n = n0 + wc * 32 + nj * 16 + lr;
#pragma unroll
      for (int rg = 0; rg < 4; rg++)
        out[(size_t)(mb + rg) * 1024 + n] = acc[mi][nj][rg] + bv2[nj];
    }
  }
}

// ---------------- flash attention over compacted keys, no-max softmax ----------------
// Q: (B,L,D) bf16 row-major, pre-scaled by 0.125*log2(e);  Kc: (B,H,Lc,Dh);  VTc: (B,H,Dh,Lc);  O: (B,L,D) bf16
__global__ __launch_bounds__(256) void attn_kernel(const unsigned short* __restrict__ Q,
                                                   const unsigned short* __restrict__ Kc,
                                                   const unsigned short* __restrict__ VTc,
                                                   const int* __restrict__ cnt,
                                                   unsigned short* __restrict__ O) {
  const int qb = blockIdx.x;   // 0..31
  const int bh = blockIdx.y;   // 0..31
  const int b = bh >> 4, h = bh & 15;
  const int t = threadIdx.x, w = t >> 6, lane = t & 63;
  const int lr = lane & 15, lg = lane >> 4;

  __shared__ __align__(16) unsigned short Ks[64 * 64];      // key rows x 128B, swizzled
  __shared__ __align__(16) unsigned short Vs[64 * 64];      // d rows x 128B (V^T), swizzled
  __shared__ __align__(16) unsigned short Ps[4][16 * 64];   // per-wave P, swizzled

  const size_t bh_off = (size_t)bh * 2048 * 64;
  const int q0 = qb * 64 + w * 16;
  const int cb = cnt[b];
  const int nkb = (cb + 63) >> 6;

  // Q fragments (B-operand of swapped QK^T): lane holds Q[q0+lr][ks*32 + lg*8 + j]
  s16x8 qf[2];
#pragma unroll
  for (int ks = 0; ks < 2; ks++)
    qf[ks] = *(const s16x8*)(Q + ((size_t)(b * 2048 + q0 + lr)) * 1024 + h * 64 + ks * 32 + lg * 8);

  f32x4 oacc[4] = {};
  float lsum = 0.f;  // per-lane partial; combined across the lg-group at the end

  const int sr = lane >> 3, sg = lane & 7;
  for (int kb = 0; kb < nkb; kb++) {
#pragma unroll
    for (int i = 0; i < 2; i++) {
      int r = (i * 4 + w) * 8 + sr;
      g2l16(Kc + bh_off + (size_t)(kb * 64 + r) * 64 + (sg ^ (r & 7)) * 8,
            (char*)Ks + (i * 4 + w) * 1024);
    }
#pragma unroll
    for (int i = 0; i < 2; i++) {
      int r = (i * 4 + w) * 8 + sr;
      g2l16(VTc + bh_off + (size_t)r * 2048 + kb * 64 + (sg ^ (r & 7)) * 8,
            (char*)Vs + (i * 4 + w) * 1024);
    }
    __syncthreads();

    // swapped QK^T: D[key][q], each lane owns one query column (q = lr)
    float p[4][4];
    __builtin_amdgcn_s_setprio(1);
#pragma unroll
    for (int t4 = 0; t4 < 4; t4++) {
      f32x4 s = {};
#pragma unroll
      for (int ks = 0; ks < 2; ks++) {
        int row = t4 * 16 + lr;
        s16x8 kf = *(const s16x8*)((const char*)Ks + row * 128 + (((ks * 4 + lg) ^ (row & 7)) * 16));
        s = __builtin_amdgcn_mfma_f32_16x16x32_bf16(kf, qf[ks], s, 0, 0, 0);
      }
      p[t4][0] = s[0]; p[t4][1] = s[1]; p[t4][2] = s[2]; p[t4][3] = s[3];
    }
    __builtin_amdgcn_s_setprio(0);

    // p = 2^score (scale folded into Q); zero out keys beyond count in the tail tile
    if ((kb + 1) * 64 <= cb) {
#pragma unroll
      for (int t4 = 0; t4 < 4; t4++)
#pragma unroll
        for (int rg = 0; rg < 4; rg++) {
          float e = __builtin_amdgcn_exp2f(p[t4][rg]);
          p[t4][rg] = e;
          lsum += e;
        }
    } else {
      const int kbase = kb * 64 + lg * 4;
#pragma unroll
      for (int t4 = 0; t4 < 4; t4++)
#pragma unroll
        for (int rg = 0; rg < 4; rg++) {
          float e = __builtin_amdgcn_exp2f(p[t4][rg]);
          e = (kbase + t4 * 16 + rg < cb) ? e : 0.f;
          p[t4][rg] = e;
          lsum += e;
        }
    }

    // write P (bf16) to per-wave LDS, swizzled rows of 128B
#pragma unroll
    for (int t4 = 0; t4 < 4; t4++) {
      u32x2 pw = {pk2bf(p[t4][0], p[t4][1]), pk2bf(p[t4][2], p[t4][3])};
      int byte = lr * 128 + ((t4 * 32 + lg * 8) ^ ((lr & 7) << 4));
      *(u32x2*)((char*)Ps + w * 2048 + byte) = pw;
    }

    // PV: O[q][d] += P[q][k] * V[k][d]
    __builtin_amdgcn_s_setprio(1);
#pragma unroll
    for (int ks = 0; ks < 2; ks++) {
      int byteA = lr * 128 + ((ks * 64 + lg * 16) ^ ((lr & 7) << 4));
      s16x8 af = *(const s16x8*)((const char*)Ps + w * 2048 + byteA);
#pragma unroll
      for (int dt = 0; dt < 4; dt++) {
        int row = dt * 16 + lr;
        s16x8 vf = *(const s16x8*)((const char*)Vs + row * 128 + (((ks * 4 + lg) ^ (row & 7)) * 16));
        oacc[dt] = __builtin_amdgcn_mfma_f32_16x16x32_bf16(af, vf, oacc[dt], 0, 0, 0);
      }
    }
    __builtin_amdgcn_s_setprio(0);
    __syncthreads();
  }

  // combine per-lane lsum partials across the 4 lanes sharing q = lr
  lsum += __shfl_xor(lsum, 16);
  lsum += __shfl_xor(lsum, 32);

  // epilogue: O = oacc / lsum  (lsum==0 -> 0, matches nan_to_num)
  float rinv[4];
#pragma unroll
  for (int rg = 0; rg < 4; rg++) {
    float ls = __shfl(lsum, lg * 4 + rg);
    rinv[rg] = (ls > 0.f) ? 1.0f / ls : 0.f;
  }
#pragma unroll
  for (int dt = 0; dt < 4; dt++)
#pragma unroll
    for (int rg = 0; rg < 4; rg++) {
      int q = q0 + lg * 4 + rg;
      int d = dt * 16 + lr;
      O[((size_t)(b * 2048 + q)) * 1024 + h * 64 + d] = f2bf(oacc[dt][rg] * rinv[rg]);
    }
}

extern "C" void kernel_launch(void* const* d_in, const int* in_sizes, int n_in,
                              void* d_out, int out_size, void* d_ws, size_t ws_size,
                              hipStream_t stream) {
  (void)in_sizes; (void)n_in; (void)out_size; (void)ws_size;
  const float* q_x = (const float*)d_in[0];
  const float* k_x = (const float*)d_in[1];
  const float* v_x = (const float*)d_in[2];
  const float* energy = (const float*)d_in[3];
  const float* Wq = (const float*)d_in[4];
  const float* bq = (const float*)d_in[5];
  const float* Wk = (const float*)d_in[6];
  const float* bk = (const float*)d_in[7];
  const float* Wv = (const float*)d_in[8];
  const float* bv = (const float*)d_in[9];
  const float* Wo = (const float*)d_in[10];
  const float* bo = (const float*)d_in[11];

  char* ws = (char*)d_ws;
  const size_t MB = 1024 * 1024;
  unsigned short* xq  = (unsigned short*)(ws + 0);        // 8MB (reused as O after Q-GEMM)
  unsigned short* xk  = (unsigned short*)(ws + 8 * MB);
  unsigned short* xv  = (unsigned short*)(ws + 16 * MB);
  unsigned short* WTq = (unsigned short*)(ws + 24 * MB);
  unsigned short* WTk = (unsigned short*)(ws + 26 * MB);
  unsigned short* WTv = (unsigned short*)(ws + 28 * MB);
  unsigned short* WTo = (unsigned short*)(ws + 30 * MB);
  unsigned short* Qb  = (unsigned short*)(ws + 32 * MB);
  unsigned short* Kc  = (unsigned short*)(ws + 40 * MB);
  unsigned short* VTc = (unsigned short*)(ws + 48 * MB);
  int* flags          = (int*)(ws + 56 * MB);
  int* pos            = (int*)(ws + 56 * MB + 16 * 1024);
  int* cnt            = (int*)(ws + 56 * MB + 32 * 1024);
  unsigned short* Ob  = xq;

  const float QSC = 0.18033688011112042f;  // 0.125 * log2(e)

  prep_kernel<<<dim3(4096, 5), 256, 0, stream>>>(q_x, k_x, v_x, energy, xq, xk, xv, flags,
                                                 Wq, Wk, Wv, Wo, WTq, WTk, WTv, WTo);
  scan_kernel<<<2, 256, 0, stream>>>(flags, pos, cnt);

  proj_qkv<<<dim3(32, 8, 3), 256, 0, stream>>>(xq, xk, xv, WTq, WTk, WTv, bq, bk, bv,
                                               Qb, Kc, VTc, pos, QSC);

  attn_kernel<<<dim3(32, 32), 256, 0, stream>>>(Qb, Kc, VTc, cnt, Ob);

  gemm_out<<<dim3(32, 16), 256, 0, stream>>>(Ob, WTo, bo, (float*)d_out);
}

// Round 7
// 107.328 us; speedup vs baseline: 1.1513x; 1.1513x over previous
//
#include <hip/hip_runtime.h>
#include <hip/hip_bf16.h>
#include <cstdint>

#define DEVI static __device__ __forceinline__

typedef __attribute__((ext_vector_type(8))) short s16x8;     // 8 bf16 (MFMA frag)
typedef __attribute__((ext_vector_type(4))) float f32x4;
typedef __attribute__((ext_vector_type(2))) unsigned int u32x2;

DEVI unsigned short f2bf(float f) {  // f32 -> bf16 bits, RNE
  union { float f; unsigned int u; } v; v.f = f;
  return (unsigned short)((v.u + 0x7FFFu + ((v.u >> 16) & 1u)) >> 16);
}

DEVI unsigned int pk2bf(float a, float b) {  // pack 2 f32 -> 2 bf16 (v_cvt_pk)
  __hip_bfloat162 h2 = __float22bfloat162_rn(float2{a, b});
  return *(unsigned int*)&h2;
}

DEVI void g2l16(const void* g, void* l) {  // async global->LDS, 16B/lane, wave-uniform LDS base
  __builtin_amdgcn_global_load_lds((const __attribute__((address_space(1))) void*)g,
                                   (__attribute__((address_space(3))) void*)l, 16, 0, 0);
}

// ---------------- prep (flat grid): cvt x3 [0,6144) + mask flags [6144,10240) + wtrans [10240,11264) ----------------
__global__ __launch_bounds__(256) void prep_kernel(const float* __restrict__ a,
                                                   const float* __restrict__ b,
                                                   const float* __restrict__ c,
                                                   const float* __restrict__ energy,
                                                   unsigned short* __restrict__ oa,
                                                   unsigned short* __restrict__ ob,
                                                   unsigned short* __restrict__ oc,
                                                   int* __restrict__ flags,
                                                   const float* __restrict__ W0,
                                                   const float* __restrict__ W1,
                                                   const float* __restrict__ W2,
                                                   const float* __restrict__ W3,
                                                   unsigned short* __restrict__ T0,
                                                   unsigned short* __restrict__ T1,
                                                   unsigned short* __restrict__ T2,
                                                   unsigned short* __restrict__ T3) {
  const int gid = blockIdx.x;
  const int t = threadIdx.x;
  __shared__ float lds[64][65];
  if (gid < 6144) {  // f32 -> bf16 cvt, 3 tensors
    const float* in = gid < 2048 ? a : gid < 4096 ? b : c;
    unsigned short* out = gid < 2048 ? oa : gid < 4096 ? ob : oc;
    const int blk = gid & 2047;
    int i = (blk * 256 + t) * 8;
    f32x4 x = *(const f32x4*)(in + i);
    f32x4 y = *(const f32x4*)(in + i + 4);
    s16x8 o;
    o[0] = (short)f2bf(x[0]); o[1] = (short)f2bf(x[1]);
    o[2] = (short)f2bf(x[2]); o[3] = (short)f2bf(x[3]);
    o[4] = (short)f2bf(y[0]); o[5] = (short)f2bf(y[1]);
    o[6] = (short)f2bf(y[2]); o[7] = (short)f2bf(y[3]);
    *(s16x8*)(out + i) = o;
    return;
  }
  if (gid < 10240) {  // mask: one energy row per block
    const int row = gid - 6144;
    f32x4 v = *(const f32x4*)(energy + (size_t)row * 1024 + t * 4);
    float s = fabsf(v[0]) + fabsf(v[1]) + fabsf(v[2]) + fabsf(v[3]);
#pragma unroll
    for (int off = 1; off < 64; off <<= 1) s += __shfl_xor(s, off);
    if ((t & 63) == 0) lds[0][t >> 6] = s;
    __syncthreads();
    if (t == 0) {
      float tot = lds[0][0] + lds[0][1] + lds[0][2] + lds[0][3];
      flags[row] = (tot * (1.0f / 1024.0f) > 0.8f) ? 1 : 0;
    }
    return;
  }
  // W (K,N) f32 -> WT (N,K) bf16: 4 matrices x 256 tiles of 64x64
  const int x = gid - 10240;
  const int z = x >> 8, rem = x & 255;
  const float* W = z == 0 ? W0 : z == 1 ? W1 : z == 2 ? W2 : W3;
  unsigned short* WT = z == 0 ? T0 : z == 1 ? T1 : z == 2 ? T2 : T3;
  const int n0 = (rem >> 4) * 64, k0 = (rem & 15) * 64;
#pragma unroll
  for (int p = 0; p < 4; p++) {
    int r = p * 16 + (t >> 4);
    int cc = (t & 15) * 4;
    f32x4 v = *(const f32x4*)(W + (size_t)(k0 + r) * 1024 + n0 + cc);
    lds[r][cc] = v[0]; lds[r][cc + 1] = v[1]; lds[r][cc + 2] = v[2]; lds[r][cc + 3] = v[3];
  }
  __syncthreads();
  const int cc = t >> 2, gk = t & 3;
#pragma unroll
  for (int hv = 0; hv < 2; hv++) {
    s16x8 o;
#pragma unroll
    for (int j = 0; j < 8; j++) o[j] = (short)f2bf(lds[gk * 16 + hv * 8 + j][cc]);
    *(s16x8*)(WT + (size_t)(n0 + cc) * 1024 + k0 + gk * 16 + hv * 8) = o;
  }
}

// ---------------- exclusive-scan of flags -> compact positions + count (1 block/batch) ----------------
__global__ __launch_bounds__(256) void scan_kernel(const int* __restrict__ flags,
                                                   int* __restrict__ pos,
                                                   int* __restrict__ cnt) {
  const int b = blockIdx.x, t = threadIdx.x;
  const int* f = flags + b * 2048;
  int loc[8], s = 0;
#pragma unroll
  for (int j = 0; j < 8; j++) { loc[j] = f[t * 8 + j]; s += loc[j]; }
  const int lane = t & 63, w = t >> 6;
  int ps = s;
#pragma unroll
  for (int off = 1; off < 64; off <<= 1) {
    int o = __shfl_up(ps, off);
    if (lane >= off) ps += o;
  }
  __shared__ int wsum[4];
  if (lane == 63) wsum[w] = ps;
  __syncthreads();
  int woff = 0;
  for (int i = 0; i < w; i++) woff += wsum[i];
  int excl = woff + ps - s;
  int* p = pos + b * 2048;
#pragma unroll
  for (int j = 0; j < 8; j++) { p[t * 8 + j] = loc[j] ? excl : -1; excl += loc[j]; }
  if (t == 255) cnt[b] = woff + ps;
}

// ================= 128x64-tile GEMM body (BK=64): 6 blocks/CU co-residency (R5-proven) ==========
#define GEMM_BODY(A, BT)                                                                        \
  const int t = threadIdx.x;                                                                    \
  const int w = t >> 6, lane = t & 63;                                                          \
  const int wr = w >> 1, wc = w & 1;                                                            \
  const int lr = lane & 15, lg = lane >> 4;                                                     \
  __shared__ __align__(16) unsigned short As[128 * 64];                                         \
  __shared__ __align__(16) unsigned short Bs[64 * 64];                                          \
  f32x4 acc[4][2] = {};                                                                         \
  const int sr = lane >> 3, sg = lane & 7;                                                      \
  for (int kt = 0; kt < 1024; kt += 64) {                                                       \
    _Pragma("unroll")                                                                           \
    for (int i = 0; i < 4; i++) {                                                               \
      int r = (i * 4 + w) * 8 + sr;                                                             \
      g2l16(A + (size_t)(m0 + r) * 1024 + kt + (sg ^ (r & 7)) * 8,                              \
            (char*)As + (i * 4 + w) * 1024);                                                    \
    }                                                                                           \
    _Pragma("unroll")                                                                           \
    for (int i = 0; i < 2; i++) {                                                               \
      int r = (i * 4 + w) * 8 + sr;                                                             \
      g2l16(BT + (size_t)(n0 + r) * 1024 + kt + (sg ^ (r & 7)) * 8,                             \
            (char*)Bs + (i * 4 + w) * 1024);                                                    \
    }                                                                                           \
    __syncthreads();                                                                            \
    _Pragma("unroll")                                                                           \
    for (int ks = 0; ks < 2; ks++) {                                                            \
      s16x8 af[4], bf[2];                                                                       \
      _Pragma("unroll")                                                                         \
      for (int mi = 0; mi < 4; mi++) {                                                          \
        int row = wr * 64 + mi * 16 + lr;                                                       \
        af[mi] = *(const s16x8*)((const char*)As + row * 128 + (((ks * 4 + lg) ^ (row & 7)) * 16)); \
      }                                                                                         \
      _Pragma("unroll")                                                                         \
      for (int nj = 0; nj < 2; nj++) {                                                          \
        int row = wc * 32 + nj * 16 + lr;                                                       \
        bf[nj] = *(const s16x8*)((const char*)Bs + row * 128 + (((ks * 4 + lg) ^ (row & 7)) * 16)); \
      }                                                                                         \
      _Pragma("unroll")                                                                         \
      for (int mi = 0; mi < 4; mi++)                                                            \
        _Pragma("unroll")                                                                       \
        for (int nj = 0; nj < 2; nj++)                                                          \
          acc[mi][nj] = __builtin_amdgcn_mfma_f32_16x16x32_bf16(af[mi], bf[nj], acc[mi][nj], 0, 0, 0); \
    }                                                                                           \
    __syncthreads();                                                                            \
  }

// ---------------- fused Q/K/V projection: z selects input/weight/epilogue ----------------
__global__ __launch_bounds__(256) void proj_qkv(const unsigned short* __restrict__ xq,
                                                const unsigned short* __restrict__ xk,
                                                const unsigned short* __restrict__ xv,
                                                const unsigned short* __restrict__ WTq,
                                                const unsigned short* __restrict__ WTk,
                                                const unsigned short* __restrict__ WTv,
                                                const float* __restrict__ bq,
                                                const float* __restrict__ bk,
                                                const float* __restrict__ bv,
                                                unsigned short* __restrict__ Qb,
                                                unsigned short* __restrict__ Kc,
                                                unsigned short* __restrict__ VTc,
                                                const int* __restrict__ pos,
                                                float qsc) {
  const int z = blockIdx.z;
  const unsigned short* A  = z == 0 ? xq : z == 1 ? xk : xv;
  const unsigned short* BT = z == 0 ? WTq : z == 1 ? WTk : WTv;
  const float* bias        = z == 0 ? bq : z == 1 ? bk : bv;
  const int m0 = blockIdx.x * 128;
  const int n0 = blockIdx.y * 64;

  GEMM_BODY(A, BT)

  float bv2[2];
#pragma unroll
  for (int nj = 0; nj < 2; nj++) bv2[nj] = bias[n0 + wc * 32 + nj * 16 + lr];

#pragma unroll
  for (int mi = 0; mi < 4; mi++) {
    const int mb = m0 + wr * 64 + mi * 16 + lg * 4;  // C row = (lane>>4)*4 + reg  [m89 layout]
#pragma unroll
    for (int nj = 0; nj < 2; nj++) {
      const int n = n0 + wc * 32 + nj * 16 + lr;     // C col = lane&15
      if (z == 0) {
#pragma unroll
        for (int rg = 0; rg < 4; rg++)
          Qb[(size_t)(mb + rg) * 1024 + n] = f2bf((acc[mi][nj][rg] + bv2[nj]) * qsc);
      } else if (z == 1) {  // K compacted (B,H,Lc,Dh)
        const int h = n >> 6, dh = n & 63;
#pragma unroll
        for (int rg = 0; rg < 4; rg++) {
          int m = mb + rg;
          int b = m >> 11;
          int cp = pos[m];
          if (cp >= 0)
            Kc[((size_t)(b * 16 + h) * 2048 + cp) * 64 + dh] = f2bf(acc[mi][nj][rg] + bv2[nj]);
        }
      } else {  // V^T compacted (B,H,Dh,Lc)
        const int h = n >> 6, dh = n & 63;
#pragma unroll
        for (int rg = 0; rg < 4; rg++) {
          int m = mb + rg;
          int b = m >> 11;
          int cp = pos[m];
          if (cp >= 0)
            VTc[((size_t)(b * 16 + h) * 64 + dh) * 2048 + cp] = f2bf(acc[mi][nj][rg] + bv2[nj]);
        }
      }
    }
  }
}

// ---------------- output projection: f32 out, row-major ----------------
__global__ __launch_bounds__(256) void gemm_out(const unsigned short* __restrict__ A,
                                                const unsigned short* __restrict__ BT,
                                                const float* __restrict__ bias,
                                                float* __restrict__ out) {
  const int m0 = blockIdx.x * 128;
  const int n0 = blockIdx.y * 64;

  GEMM_BODY(A, BT)

  float bv2[2];
#pragma unroll
  for (int nj = 0; nj < 2; nj++) bv2[nj] = bias[n0 + wc * 32 + nj * 16 + lr];

#pragma unroll
  for (int mi = 0; mi < 4; mi++) {
    const int mb = m0 + wr * 64 + mi * 16 + lg * 4;
#pragma unroll
    for (int nj = 0; nj < 2; nj++) {
      const int n = n0 + wc * 32 + nj * 16 + lr;
#pragma unroll
      for (int rg = 0; rg < 4; rg++)
        out[(size_t)(mb + rg) * 1024 + n] = acc[mi][nj][rg] + bv2[nj];
    }
  }
}

// ---------------- flash attention over compacted keys, no-max softmax ----------------
// Grid: x = bh (XCD = bh%8 -> per-head K/V L2 locality), y = qb.
__global__ __launch_bounds__(256) void attn_kernel(const unsigned short* __restrict__ Q,
                                                   const unsigned short* __restrict__ Kc,
                                                   const unsigned short* __restrict__ VTc,
                                                   const int* __restrict__ cnt,
                                                   unsigned short* __restrict__ O) {
  const int bh = blockIdx.x;   // 0..31  (fast dim -> same head pinned to one XCD)
  const int qb = blockIdx.y;   // 0..31
  const int b = bh >> 4, h = bh & 15;
  const int t = threadIdx.x, w = t >> 6, lane = t & 63;
  const int lr = lane & 15, lg = lane >> 4;

  __shared__ __align__(16) unsigned short Ks[64 * 64];      // key rows x 128B, swizzled
  __shared__ __align__(16) unsigned short Vs[64 * 64];      // d rows x 128B (V^T), swizzled
  __shared__ __align__(16) unsigned short Ps[4][16 * 64];   // per-wave P, swizzled

  const size_t bh_off = (size_t)bh * 2048 * 64;
  const int q0 = qb * 64 + w * 16;
  const int cb = cnt[b];
  const int nkb = (cb + 63) >> 6;

  // Q fragments (B-operand of swapped QK^T): lane holds Q[q0+lr][ks*32 + lg*8 + j]
  s16x8 qf[2];
#pragma unroll
  for (int ks = 0; ks < 2; ks++)
    qf[ks] = *(const s16x8*)(Q + ((size_t)(b * 2048 + q0 + lr)) * 1024 + h * 64 + ks * 32 + lg * 8);

  f32x4 oacc[4] = {};
  float lsum = 0.f;  // per-lane partial; combined across the lg-group at the end

  const int sr = lane >> 3, sg = lane & 7;
  for (int kb = 0; kb < nkb; kb++) {
#pragma unroll
    for (int i = 0; i < 2; i++) {
      int r = (i * 4 + w) * 8 + sr;
      g2l16(Kc + bh_off + (size_t)(kb * 64 + r) * 64 + (sg ^ (r & 7)) * 8,
            (char*)Ks + (i * 4 + w) * 1024);
    }
#pragma unroll
    for (int i = 0; i < 2; i++) {
      int r = (i * 4 + w) * 8 + sr;
      g2l16(VTc + bh_off + (size_t)r * 2048 + kb * 64 + (sg ^ (r & 7)) * 8,
            (char*)Vs + (i * 4 + w) * 1024);
    }
    __syncthreads();

    // swapped QK^T: D[key][q], each lane owns one query column (q = lr)
    float p[4][4];
    __builtin_amdgcn_s_setprio(1);
#pragma unroll
    for (int t4 = 0; t4 < 4; t4++) {
      f32x4 s = {};
#pragma unroll
      for (int ks = 0; ks < 2; ks++) {
        int row = t4 * 16 + lr;
        s16x8 kf = *(const s16x8*)((const char*)Ks + row * 128 + (((ks * 4 + lg) ^ (row & 7)) * 16));
        s = __builtin_amdgcn_mfma_f32_16x16x32_bf16(kf, qf[ks], s, 0, 0, 0);
      }
      p[t4][0] = s[0]; p[t4][1] = s[1]; p[t4][2] = s[2]; p[t4][3] = s[3];
    }
    __builtin_amdgcn_s_setprio(0);

    // p = 2^score (scale folded into Q); zero out keys beyond count in the tail tile
    if ((kb + 1) * 64 <= cb) {
#pragma unroll
      for (int t4 = 0; t4 < 4; t4++)
#pragma unroll
        for (int rg = 0; rg < 4; rg++) {
          float e = __builtin_amdgcn_exp2f(p[t4][rg]);
          p[t4][rg] = e;
          lsum += e;
        }
    } else {
      const int kbase = kb * 64 + lg * 4;
#pragma unroll
      for (int t4 = 0; t4 < 4; t4++)
#pragma unroll
        for (int rg = 0; rg < 4; rg++) {
          float e = __builtin_amdgcn_exp2f(p[t4][rg]);
          e = (kbase + t4 * 16 + rg < cb) ? e : 0.f;
          p[t4][rg] = e;
          lsum += e;
        }
    }

    // write P (bf16) to per-wave LDS, swizzled rows of 128B
#pragma unroll
    for (int t4 = 0; t4 < 4; t4++) {
      u32x2 pw = {pk2bf(p[t4][0], p[t4][1]), pk2bf(p[t4][2], p[t4][3])};
      int byte = lr * 128 + ((t4 * 32 + lg * 8) ^ ((lr & 7) << 4));
      *(u32x2*)((char*)Ps + w * 2048 + byte) = pw;
    }

    // PV: O[q][d] += P[q][k] * V[k][d]
    __builtin_amdgcn_s_setprio(1);
#pragma unroll
    for (int ks = 0; ks < 2; ks++) {
      int byteA = lr * 128 + ((ks * 64 + lg * 16) ^ ((lr & 7) << 4));
      s16x8 af = *(const s16x8*)((const char*)Ps + w * 2048 + byteA);
#pragma unroll
      for (int dt = 0; dt < 4; dt++) {
        int row = dt * 16 + lr;
        s16x8 vf = *(const s16x8*)((const char*)Vs + row * 128 + (((ks * 4 + lg) ^ (row & 7)) * 16));
        oacc[dt] = __builtin_amdgcn_mfma_f32_16x16x32_bf16(af, vf, oacc[dt], 0, 0, 0);
      }
    }
    __builtin_amdgcn_s_setprio(0);
    __syncthreads();
  }

  // combine per-lane lsum partials across the 4 lanes sharing q = lr
  lsum += __shfl_xor(lsum, 16);
  lsum += __shfl_xor(lsum, 32);

  // epilogue: O = oacc / lsum  (lsum==0 -> 0, matches nan_to_num)
  float rinv[4];
#pragma unroll
  for (int rg = 0; rg < 4; rg++) {
    float ls = __shfl(lsum, lg * 4 + rg);
    rinv[rg] = (ls > 0.f) ? 1.0f / ls : 0.f;
  }
#pragma unroll
  for (int dt = 0; dt < 4; dt++)
#pragma unroll
    for (int rg = 0; rg < 4; rg++) {
      int q = q0 + lg * 4 + rg;
      int d = dt * 16 + lr;
      O[((size_t)(b * 2048 + q)) * 1024 + h * 64 + d] = f2bf(oacc[dt][rg] * rinv[rg]);
    }
}

extern "C" void kernel_launch(void* const* d_in, const int* in_sizes, int n_in,
                              void* d_out, int out_size, void* d_ws, size_t ws_size,
                              hipStream_t stream) {
  (void)in_sizes; (void)n_in; (void)out_size; (void)ws_size;
  const float* q_x = (const float*)d_in[0];
  const float* k_x = (const float*)d_in[1];
  const float* v_x = (const float*)d_in[2];
  const float* energy = (const float*)d_in[3];
  const float* Wq = (const float*)d_in[4];
  const float* bq = (const float*)d_in[5];
  const float* Wk = (const float*)d_in[6];
  const float* bk = (const float*)d_in[7];
  const float* Wv = (const float*)d_in[8];
  const float* bv = (const float*)d_in[9];
  const float* Wo = (const float*)d_in[10];
  const float* bo = (const float*)d_in[11];

  char* ws = (char*)d_ws;
  const size_t MB = 1024 * 1024;
  unsigned short* xq  = (unsigned short*)(ws + 0);        // 8MB (reused as O after Q-GEMM)
  unsigned short* xk  = (unsigned short*)(ws + 8 * MB);
  unsigned short* xv  = (unsigned short*)(ws + 16 * MB);
  unsigned short* WTq = (unsigned short*)(ws + 24 * MB);
  unsigned short* WTk = (unsigned short*)(ws + 26 * MB);
  unsigned short* WTv = (unsigned short*)(ws + 28 * MB);
  unsigned short* WTo = (unsigned short*)(ws + 30 * MB);
  unsigned short* Qb  = (unsigned short*)(ws + 32 * MB);
  unsigned short* Kc  = (unsigned short*)(ws + 40 * MB);
  unsigned short* VTc = (unsigned short*)(ws + 48 * MB);
  int* flags          = (int*)(ws + 56 * MB);
  int* pos            = (int*)(ws + 56 * MB + 16 * 1024);
  int* cnt            = (int*)(ws + 56 * MB + 32 * 1024);
  unsigned short* Ob  = xq;

  const float QSC = 0.18033688011112042f;  // 0.125 * log2(e)

  prep_kernel<<<11264, 256, 0, stream>>>(q_x, k_x, v_x, energy, xq, xk, xv, flags,
                                         Wq, Wk, Wv, Wo, WTq, WTk, WTv, WTo);
  scan_kernel<<<2, 256, 0, stream>>>(flags, pos, cnt);

  proj_qkv<<<dim3(32, 16, 3), 256, 0, stream>>>(xq, xk, xv, WTq, WTk, WTv, bq, bk, bv,
                                                Qb, Kc, VTc, pos, QSC);

  attn_kernel<<<dim3(32, 32), 256, 0, stream>>>(Qb, Kc, VTc, cnt, Ob);

  gemm_out<<<dim3(32, 16), 256, 0, stream>>>(Ob, WTo, bo, (float*)d_out);
}